// Round 1
// 530.139 us; speedup vs baseline: 1.0706x; 1.0706x over previous
//
#include <hip/hip_runtime.h>
#include <hip/hip_bf16.h>
#include <stdint.h>
#include <math.h>

typedef __bf16 bf16_t;
typedef __bf16 bf16x8 __attribute__((ext_vector_type(8)));
typedef __bf16 bf16x4 __attribute__((ext_vector_type(4)));
typedef float  f32x4  __attribute__((ext_vector_type(4)));

#define S_CTX 2048
#define NH    16
#define DM    1024
#define DH    64

// ws layout (bf16 element offsets)
#define WS_WT   0                      // wqT, wkT, wvT: 3 * 16*64*1024  (e,k)
#define WS_WOT  (3*1048576)            // woT: 16*1024*64  (d,e)
#define WS_Q    (4*1048576)            // (h,s,e) 16*2048*64
#define WS_K    (WS_Q  + 2097152)
#define WS_VT   (WS_K  + 2097152)      // (h,e,s)
#define WS_Z    (WS_VT + 2097152)      // (h,s,e)

// async global->LDS, 16B per lane. LDS dest = uniform base + lane*16 (linear).
__device__ __forceinline__ void async16(void* lds, const void* g) {
  __builtin_amdgcn_global_load_lds(
      (const __attribute__((address_space(1))) unsigned int*)g,
      (__attribute__((address_space(3))) unsigned int*)lds, 16, 0, 0);
}

// ---------------- weight transpose: fp32 W(n,R,C) -> bf16 WT(n,C,R) ---------
__global__ __launch_bounds__(256) void transpose_w(const float* __restrict__ wq,
                                                   const float* __restrict__ wk,
                                                   const float* __restrict__ wv,
                                                   const float* __restrict__ wo,
                                                   bf16_t* __restrict__ ws) {
  __shared__ bf16_t tl[64 * 68];
  int m = blockIdx.z, h = blockIdx.y, t = blockIdx.x, tid = threadIdx.x;
  const float* in; bf16_t* out; int R, C, r0, c0;
  if (m < 3) { in = (m == 0) ? wq : (m == 1) ? wk : wv; out = ws + m * 1048576;
               R = 1024; C = 64; r0 = t * 64; c0 = 0; }
  else       { in = wo; out = ws + WS_WOT; R = 64; C = 1024; r0 = 0; c0 = t * 64; }
  in  += h * 65536;
  out += h * 65536;
#pragma unroll
  for (int i = 0; i < 4; i++) {
    int idx = tid + i * 256;
    int r = idx >> 4, c = (idx & 15) << 2;
    float4 v = *reinterpret_cast<const float4*>(in + (r0 + r) * C + c0 + c);
    bf16x4 b;
    b[0] = (bf16_t)v.x; b[1] = (bf16_t)v.y; b[2] = (bf16_t)v.z; b[3] = (bf16_t)v.w;
    *reinterpret_cast<bf16x4*>(tl + r * 68 + c) = b;
  }
  __syncthreads();
#pragma unroll
  for (int i = 0; i < 2; i++) {
    int oc = (tid >> 3) + i * 32, ok = (tid & 7) << 3;
    bf16x8 v;
#pragma unroll
    for (int j = 0; j < 8; j++) v[j] = tl[(ok + j) * 68 + oc];
    *reinterpret_cast<bf16x8*>(out + (c0 + oc) * R + r0 + ok) = v;
  }
}

// ---------------- QKV projection + rotary -----------------------------------
// 128 s-rows x 64 cols per block, K-step 64.
// A staged as raw fp32 via global_load_lds (no VGPR roundtrip), source-XOR-
// swizzled so fragment reads are bank-conflict-free; converted to bf16 at
// ds_read time. B staged via global_load_lds (bf16), same swizzle trick.
__global__ __launch_bounds__(256) void qkv_proj(const float* __restrict__ xq,
                                                const float* __restrict__ xk,
                                                const float* __restrict__ xv,
                                                const float* __restrict__ bq,
                                                const float* __restrict__ bk,
                                                const float* __restrict__ bv,
                                                bf16_t* __restrict__ ws) {
  __shared__ __attribute__((aligned(16))) float  Al[128 * 64];  // (s,k) fp32, chunk^=(s&15)
  __shared__ __attribute__((aligned(16))) bf16_t Bl[64 * 64];   // (e,k) bf16, chunk^=(e&7)
  int st = blockIdx.x, h = blockIdx.y, m = blockIdx.z;
  int tid = threadIdx.x, w = tid >> 6, lane = tid & 63, quad = lane >> 4, l15 = lane & 15;
  const float*  in   = (m == 0) ? xq : (m == 1) ? xk : xv;
  const bf16_t* wT   = ws + m * 1048576 + h * 65536;
  const float*  bias = (m == 0) ? bq : (m == 1) ? bk : bv;
  int s0 = st * 128;
  const float* Ab = in + (s0 * 16 + h) * 1024;   // row stride 16*1024 floats

  // per-lane staging geometry
  int a_r = lane >> 4;     // row within 4-row group (A: 64 fp32 = 256B/row)
  int a_j = lane & 15;     // 16B chunk within A row
  int b_r = lane >> 3;     // row within 8-row group (B: 64 bf16 = 128B/row)
  int b_j = lane & 7;      // 16B chunk within B row

  f32x4 acc[2][4];
#pragma unroll
  for (int rt = 0; rt < 2; rt++)
#pragma unroll
    for (int t = 0; t < 4; t++) acc[rt][t] = (f32x4){0.f, 0.f, 0.f, 0.f};

  for (int k0 = 0; k0 < 1024; k0 += 64) {
    // stage A: 128x64 fp32, 32 wave-instructions (8/wave), zero dest regs
#pragma unroll
    for (int i = 0; i < 8; i++) {
      int g = w * 8 + i;                 // instr index 0..31 (uniform per wave)
      int r = g * 4 + a_r;               // 0..127
      int c = a_j ^ (r & 15);            // source pre-swizzle
      async16(Al + g * 256, Ab + r * 16384 + k0 + c * 4);
    }
    // stage B: 64x64 bf16, 8 wave-instructions (2/wave)
#pragma unroll
    for (int i = 0; i < 2; i++) {
      int g = w * 2 + i;                 // 0..7
      int r = g * 8 + b_r;               // 0..63
      int c = b_j ^ (r & 7);
      async16(Bl + g * 512, wT + r * 1024 + k0 + c * 8);
    }
    __syncthreads();                     // drains vmcnt; LDS tiles ready
#pragma unroll
    for (int ks = 0; ks < 2; ks++) {
      // A fragments: rows (w*32 [+16]) + l15; (row & 15) == l15 for both
      int cA0 = ((ks * 8 + quad * 2) ^ l15) << 2;   // swizzled chunk -> fp32 elems
      int cA1 = cA0 ^ 4;                            // (chunk+1)^l15
      const float* Ar0 = Al + (w * 32 + l15) * 64;
      const float* Ar1 = Ar0 + 16 * 64;
      f32x4 lo0 = *reinterpret_cast<const f32x4*>(Ar0 + cA0);
      f32x4 hi0 = *reinterpret_cast<const f32x4*>(Ar0 + cA1);
      f32x4 lo1 = *reinterpret_cast<const f32x4*>(Ar1 + cA0);
      f32x4 hi1 = *reinterpret_cast<const f32x4*>(Ar1 + cA1);
      bf16x8 a0, a1;
#pragma unroll
      for (int jj = 0; jj < 4; jj++) {
        a0[jj] = (bf16_t)lo0[jj]; a0[jj + 4] = (bf16_t)hi0[jj];
        a1[jj] = (bf16_t)lo1[jj]; a1[jj + 4] = (bf16_t)hi1[jj];
      }
#pragma unroll
      for (int t = 0; t < 4; t++) {
        int rB = t * 16 + l15;                       // (rB & 7) == (l15 & 7)
        bf16x8 bb = *reinterpret_cast<const bf16x8*>(
            Bl + rB * 64 + (((ks * 4 + quad) ^ (l15 & 7)) << 3));
        acc[0][t] = __builtin_amdgcn_mfma_f32_16x16x32_bf16(a0, bb, acc[0][t], 0, 0, 0);
        acc[1][t] = __builtin_amdgcn_mfma_f32_16x16x32_bf16(a1, bb, acc[1][t], 0, 0, 0);
      }
    }
    __syncthreads();                     // LDS consumed; safe to overwrite
  }
  // bias
#pragma unroll
  for (int t = 0; t < 4; t++) {
    float bval = bias[h * 64 + t * 16 + l15];
#pragma unroll
    for (int rt = 0; rt < 2; rt++)
#pragma unroll
      for (int r = 0; r < 4; r++) acc[rt][t][r] += bval;
  }

  if (m < 2) {
    bf16_t* outp = ws + ((m == 0) ? WS_Q : WS_K) + h * (2048 * 64);
#pragma unroll
    for (int t = 0; t < 2; t++) {
      int c_lo = t * 16 + l15;
      float freq = powf(10000.0f, (float)c_lo * (1.0f / 32.0f));
#pragma unroll
      for (int rt = 0; rt < 2; rt++)
#pragma unroll
        for (int r = 0; r < 4; r++) {
          int s = s0 + w * 32 + rt * 16 + quad * 4 + r;
          float ang = (float)s / freq;
          float sv = sinf(ang), cv = cosf(ang);
          float xl = acc[rt][t][r], xh = acc[rt][t + 2][r];
          acc[rt][t][r]     = xl * cv - xh * sv;
          acc[rt][t + 2][r] = xh * cv + xl * sv;
        }
    }
#pragma unroll
    for (int rt = 0; rt < 2; rt++)
#pragma unroll
      for (int t = 0; t < 4; t++)
#pragma unroll
        for (int r = 0; r < 4; r++) {
          int s = s0 + w * 32 + rt * 16 + quad * 4 + r;
          outp[s * 64 + t * 16 + l15] = (bf16_t)acc[rt][t][r];
        }
  } else {
    bf16_t* outp = ws + WS_VT + h * (64 * 2048);
#pragma unroll
    for (int rt = 0; rt < 2; rt++)
#pragma unroll
      for (int t = 0; t < 4; t++) {
        int e = t * 16 + l15;
        int sbase = s0 + w * 32 + rt * 16 + quad * 4;
        bf16x4 v;
#pragma unroll
        for (int r = 0; r < 4; r++) v[r] = (bf16_t)acc[rt][t][r];
        *reinterpret_cast<bf16x4*>(outp + e * 2048 + sbase) = v;
      }
  }
}

// ---------------- flash attention (causal, online softmax), KV-step 128 -----
__global__ __launch_bounds__(256) void attn(bf16_t* __restrict__ ws) {
  __shared__ bf16_t Ql[64 * 72];      // (q, e)
  __shared__ bf16_t Kl[128 * 72];     // (kv, e)
  __shared__ bf16_t Vl[64 * 136];     // (e, kv)
  __shared__ bf16_t Pl[4 * 16 * 136]; // per-wave (q, kv)
  int qt = blockIdx.x, h = blockIdx.y;
  int tid = threadIdx.x, w = tid >> 6, lane = tid & 63, quad = lane >> 4, l15 = lane & 15;
  const bf16_t* qp  = ws + WS_Q  + h * 131072;
  const bf16_t* kp  = ws + WS_K  + h * 131072;
  const bf16_t* vtp = ws + WS_VT + h * 131072;
  bf16_t*       zp  = ws + WS_Z  + h * 131072;
  int s0 = qt * 64;

  // stage Q: 64x64
#pragma unroll
  for (int i = 0; i < 2; i++) {
    int g = tid + i * 256;
    int r = g >> 3, cg = g & 7;
    *reinterpret_cast<uint4*>(Ql + r * 72 + cg * 8) =
        *reinterpret_cast<const uint4*>(qp + (s0 + r) * 64 + cg * 8);
  }

  f32x4 o[4];
#pragma unroll
  for (int t = 0; t < 4; t++) o[t] = (f32x4){0.f, 0.f, 0.f, 0.f};
  float m_i[4], l_i[4];
#pragma unroll
  for (int r = 0; r < 4; r++) { m_i[r] = -__builtin_inff(); l_i[r] = 0.f; }
  bf16_t* Plw = Pl + w * (16 * 136);

  int jmax = qt >> 1;
  for (int j = 0; j <= jmax; j++) {
    __syncthreads();
    // stage K: 128 x 64
#pragma unroll
    for (int i = 0; i < 4; i++) {
      int g = tid + i * 256;
      int r = g >> 3, cg = g & 7;
      *reinterpret_cast<uint4*>(Kl + r * 72 + cg * 8) =
          *reinterpret_cast<const uint4*>(kp + (j * 128 + r) * 64 + cg * 8);
    }
    // stage V^T: 64 x 128
#pragma unroll
    for (int i = 0; i < 4; i++) {
      int g = tid + i * 256;
      int r = g >> 4, cg = g & 15;
      *reinterpret_cast<uint4*>(Vl + r * 136 + cg * 8) =
          *reinterpret_cast<const uint4*>(vtp + r * 2048 + j * 128 + cg * 8);
    }
    __syncthreads();

    // scores: 16 q-rows/wave x 128 kv
    f32x4 sc[8];
#pragma unroll
    for (int t = 0; t < 8; t++) sc[t] = (f32x4){0.f, 0.f, 0.f, 0.f};
#pragma unroll
    for (int ks = 0; ks < 2; ks++) {
      bf16x8 af = *reinterpret_cast<const bf16x8*>(Ql + (w * 16 + l15) * 72 + ks * 32 + quad * 8);
#pragma unroll
      for (int t = 0; t < 8; t++) {
        bf16x8 bfr = *reinterpret_cast<const bf16x8*>(Kl + (t * 16 + l15) * 72 + ks * 32 + quad * 8);
        sc[t] = __builtin_amdgcn_mfma_f32_16x16x32_bf16(af, bfr, sc[t], 0, 0, 0);
      }
    }
    // scale + causal mask
#pragma unroll
    for (int t = 0; t < 8; t++) {
      int kvc = j * 128 + t * 16 + l15;
#pragma unroll
      for (int r = 0; r < 4; r++) {
        int qrow = s0 + w * 16 + quad * 4 + r;
        float sv = sc[t][r] * 0.125f;
        sc[t][r] = (kvc > qrow) ? -1e30f : sv;
      }
    }
    // online softmax (rows shared by 16 lanes of a quad)
    float alpha[4];
#pragma unroll
    for (int r = 0; r < 4; r++) {
      float mx = sc[0][r];
#pragma unroll
      for (int t = 1; t < 8; t++) mx = fmaxf(mx, sc[t][r]);
#pragma unroll
      for (int off = 1; off < 16; off <<= 1) mx = fmaxf(mx, __shfl_xor(mx, off));
      float mn = fmaxf(m_i[r], mx);
      alpha[r] = __expf(m_i[r] - mn);
      float rs = 0.f;
#pragma unroll
      for (int t = 0; t < 8; t++) { sc[t][r] = __expf(sc[t][r] - mn); rs += sc[t][r]; }
#pragma unroll
      for (int off = 1; off < 16; off <<= 1) rs += __shfl_xor(rs, off);
      l_i[r] = l_i[r] * alpha[r] + rs;
      m_i[r] = mn;
    }
    // P (C-layout) -> wave-private LDS (A-layout); no barrier needed
#pragma unroll
    for (int t = 0; t < 8; t++)
#pragma unroll
      for (int r = 0; r < 4; r++)
        Plw[(quad * 4 + r) * 136 + t * 16 + l15] = (bf16_t)sc[t][r];
    // rescale O
#pragma unroll
    for (int t = 0; t < 4; t++)
#pragma unroll
      for (int r = 0; r < 4; r++) o[t][r] *= alpha[r];
    // O += P V  (K-dim = 128)
#pragma unroll
    for (int ks = 0; ks < 4; ks++) {
      bf16x8 af = *reinterpret_cast<const bf16x8*>(Plw + l15 * 136 + ks * 32 + quad * 8);
#pragma unroll
      for (int t = 0; t < 4; t++) {
        bf16x8 bfr = *reinterpret_cast<const bf16x8*>(Vl + (t * 16 + l15) * 136 + ks * 32 + quad * 8);
        o[t] = __builtin_amdgcn_mfma_f32_16x16x32_bf16(af, bfr, o[t], 0, 0, 0);
      }
    }
  }
  // normalize + store z (h,s,e)
  float inv[4];
#pragma unroll
  for (int r = 0; r < 4; r++) inv[r] = 1.0f / l_i[r];
#pragma unroll
  for (int t = 0; t < 4; t++)
#pragma unroll
    for (int r = 0; r < 4; r++) {
      int s = s0 + w * 16 + quad * 4 + r;
      zp[s * 64 + t * 16 + l15] = (bf16_t)(o[t][r] * inv[r]);
    }
}

// ---------------- output projection (fp32 out), 128x128 tile ----------------
__global__ __launch_bounds__(256) void out_proj(const bf16_t* __restrict__ ws,
                                                const float* __restrict__ bo,
                                                float* __restrict__ out) {
  __shared__ bf16_t Zl[128 * 72];   // (s, e)
  __shared__ bf16_t Wl[128 * 72];   // (d, e)
  int st = blockIdx.x >> 3, dt = blockIdx.x & 7, h = blockIdx.y;
  int tid = threadIdx.x, w = tid >> 6, lane = tid & 63, quad = lane >> 4, l15 = lane & 15;
  int s0 = st * 128, d0 = dt * 128;
  const bf16_t* zp = ws + WS_Z + h * 131072;
  const bf16_t* wo = ws + WS_WOT + h * 65536;
#pragma unroll
  for (int i = 0; i < 4; i++) {
    int g = tid + i * 256;
    int r = g >> 3, cg = g & 7;
    *reinterpret_cast<uint4*>(Zl + r * 72 + cg * 8) =
        *reinterpret_cast<const uint4*>(zp + (s0 + r) * 64 + cg * 8);
  }
#pragma unroll
  for (int i = 0; i < 4; i++) {
    int g = tid + i * 256;
    int r = g >> 3, cg = g & 7;
    *reinterpret_cast<uint4*>(Wl + r * 72 + cg * 8) =
        *reinterpret_cast<const uint4*>(wo + (d0 + r) * 64 + cg * 8);
  }
  __syncthreads();
  f32x4 acc[2][8];
#pragma unroll
  for (int rt = 0; rt < 2; rt++)
#pragma unroll
    for (int t = 0; t < 8; t++) acc[rt][t] = (f32x4){0.f, 0.f, 0.f, 0.f};
#pragma unroll
  for (int ks = 0; ks < 2; ks++) {
    bf16x8 a0 = *reinterpret_cast<const bf16x8*>(Zl + (w * 32 + l15) * 72 + ks * 32 + quad * 8);
    bf16x8 a1 = *reinterpret_cast<const bf16x8*>(Zl + (w * 32 + 16 + l15) * 72 + ks * 32 + quad * 8);
#pragma unroll
    for (int t = 0; t < 8; t++) {
      bf16x8 bb = *reinterpret_cast<const bf16x8*>(Wl + (t * 16 + l15) * 72 + ks * 32 + quad * 8);
      acc[0][t] = __builtin_amdgcn_mfma_f32_16x16x32_bf16(a0, bb, acc[0][t], 0, 0, 0);
      acc[1][t] = __builtin_amdgcn_mfma_f32_16x16x32_bf16(a1, bb, acc[1][t], 0, 0, 0);
    }
  }
#pragma unroll
  for (int t = 0; t < 8; t++) {
    float bval = bo[d0 + t * 16 + l15] * (1.0f / 16.0f);
#pragma unroll
    for (int rt = 0; rt < 2; rt++)
#pragma unroll
      for (int r = 0; r < 4; r++) {
        int s = s0 + w * 32 + rt * 16 + quad * 4 + r;
        out[(s * 16 + h) * 1024 + d0 + t * 16 + l15] = acc[rt][t][r] + bval;
      }
  }
}

extern "C" void kernel_launch(void* const* d_in, const int* in_sizes, int n_in,
                              void* d_out, int out_size, void* d_ws, size_t ws_size,
                              hipStream_t stream) {
  const float* xq = (const float*)d_in[0];
  const float* xk = (const float*)d_in[1];
  const float* xv = (const float*)d_in[2];
  const float* wq = (const float*)d_in[3];
  const float* bq = (const float*)d_in[4];
  const float* wk = (const float*)d_in[5];
  const float* bk = (const float*)d_in[6];
  const float* wv = (const float*)d_in[7];
  const float* bv = (const float*)d_in[8];
  const float* wo = (const float*)d_in[9];
  const float* bo = (const float*)d_in[10];
  bf16_t* ws  = (bf16_t*)d_ws;
  float*  out = (float*)d_out;

  hipLaunchKernelGGL(transpose_w, dim3(16, 16, 4), dim3(256), 0, stream, wq, wk, wv, wo, ws);
  hipLaunchKernelGGL(qkv_proj,    dim3(16, 16, 3), dim3(256), 0, stream, xq, xk, xv, bq, bk, bv, ws);
  hipLaunchKernelGGL(attn,        dim3(32, 16),    dim3(256), 0, stream, ws);
  hipLaunchKernelGGL(out_proj,    dim3(128, 16),   dim3(256), 0, stream, ws, bo, out);
}

// Round 2
// 524.519 us; speedup vs baseline: 1.0821x; 1.0107x over previous
//
#include <hip/hip_runtime.h>
#include <hip/hip_bf16.h>
#include <stdint.h>
#include <math.h>

typedef __bf16 bf16_t;
typedef __bf16 bf16x8 __attribute__((ext_vector_type(8)));
typedef __bf16 bf16x4 __attribute__((ext_vector_type(4)));
typedef float  f32x4  __attribute__((ext_vector_type(4)));

#define S_CTX 2048
#define NH    16
#define DM    1024
#define DH    64

// ws layout (bf16 element offsets)
#define WS_WT   0                      // wqT, wkT, wvT: 3 * 16*64*1024  (e,k)
#define WS_WOT  (3*1048576)            // woT: 16*1024*64  (d,e)
#define WS_Q    (4*1048576)            // (h,s,e) 16*2048*64
#define WS_K    (WS_Q  + 2097152)
#define WS_VT   (WS_K  + 2097152)      // (h,e,s)
#define WS_Z    (WS_VT + 2097152)      // (h,s,e)

// async global->LDS, 16B per lane. LDS dest = uniform base + lane*16 (linear).
__device__ __forceinline__ void async16(void* lds, const void* g) {
  __builtin_amdgcn_global_load_lds(
      (const __attribute__((address_space(1))) unsigned int*)g,
      (__attribute__((address_space(3))) unsigned int*)lds, 16, 0, 0);
}

// ---------------- weight transpose: fp32 W(n,R,C) -> bf16 WT(n,C,R) ---------
__global__ __launch_bounds__(256) void transpose_w(const float* __restrict__ wq,
                                                   const float* __restrict__ wk,
                                                   const float* __restrict__ wv,
                                                   const float* __restrict__ wo,
                                                   bf16_t* __restrict__ ws) {
  __shared__ bf16_t tl[64 * 68];
  int m = blockIdx.z, h = blockIdx.y, t = blockIdx.x, tid = threadIdx.x;
  const float* in; bf16_t* out; int R, C, r0, c0;
  if (m < 3) { in = (m == 0) ? wq : (m == 1) ? wk : wv; out = ws + m * 1048576;
               R = 1024; C = 64; r0 = t * 64; c0 = 0; }
  else       { in = wo; out = ws + WS_WOT; R = 64; C = 1024; r0 = 0; c0 = t * 64; }
  in  += h * 65536;
  out += h * 65536;
#pragma unroll
  for (int i = 0; i < 4; i++) {
    int idx = tid + i * 256;
    int r = idx >> 4, c = (idx & 15) << 2;
    float4 v = *reinterpret_cast<const float4*>(in + (r0 + r) * C + c0 + c);
    bf16x4 b;
    b[0] = (bf16_t)v.x; b[1] = (bf16_t)v.y; b[2] = (bf16_t)v.z; b[3] = (bf16_t)v.w;
    *reinterpret_cast<bf16x4*>(tl + r * 68 + c) = b;
  }
  __syncthreads();
#pragma unroll
  for (int i = 0; i < 2; i++) {
    int oc = (tid >> 3) + i * 32, ok = (tid & 7) << 3;
    bf16x8 v;
#pragma unroll
    for (int j = 0; j < 8; j++) v[j] = tl[(ok + j) * 68 + oc];
    *reinterpret_cast<bf16x8*>(out + (c0 + oc) * R + r0 + ok) = v;
  }
}

// ---------------- QKV projection + rotary -----------------------------------
// 128 s-rows x 64 cols per block, K-step 32, DOUBLE-BUFFERED with counted
// vmcnt so prefetch loads stay in flight across the barrier (T3/T4 2-phase).
// A staged raw fp32 via global_load_lds, source-XOR-swizzled (chunk ^= row&7);
// B staged bf16 (chunk ^= (row>>1)&3). Both conflict-free (2-way) on read.
__global__ __launch_bounds__(256, 4) void qkv_proj(const float* __restrict__ xq,
                                                   const float* __restrict__ xk,
                                                   const float* __restrict__ xv,
                                                   const float* __restrict__ bq,
                                                   const float* __restrict__ bk,
                                                   const float* __restrict__ bv,
                                                   bf16_t* __restrict__ ws) {
  __shared__ __attribute__((aligned(16))) float  Al[2 * 128 * 32];  // 2x16KB
  __shared__ __attribute__((aligned(16))) bf16_t Bl[2 * 64 * 32];   // 2x4KB
  int st = blockIdx.x, h = blockIdx.y, m = blockIdx.z;
  int tid = threadIdx.x, w = tid >> 6, lane = tid & 63, quad = lane >> 4, l15 = lane & 15;
  const float*  in   = (m == 0) ? xq : (m == 1) ? xk : xv;
  const bf16_t* wT   = ws + m * 1048576 + h * 65536;
  const float*  bias = (m == 0) ? bq : (m == 1) ? bk : bv;
  int s0 = st * 128;
  const float* Ab = in + (s0 * 16 + h) * 1024;   // row stride 16*1024 floats

  // per-lane staging geometry (BK=32)
  int a_r = lane >> 3;                 // 0..7  row within 8-row group (A row = 128B)
  int a_c = (lane & 7) ^ a_r;          // source pre-swizzle: chunk ^= row&7
  int b_r = lane >> 2;                 // 0..15 row within 16-row group (B row = 64B)
  int b_c = (lane & 3) ^ ((lane >> 3) & 3);   // chunk ^= (row>>1)&3

  f32x4 acc[2][4];
#pragma unroll
  for (int rt = 0; rt < 2; rt++)
#pragma unroll
    for (int t = 0; t < 4; t++) acc[rt][t] = (f32x4){0.f, 0.f, 0.f, 0.f};

  auto stage = [&](int buf, int k0) {
    float*  Ad = Al + buf * 4096;
    bf16_t* Bd = Bl + buf * 2048;
#pragma unroll
    for (int i = 0; i < 4; i++) {
      int g = w * 4 + i;               // 0..15, covers rows g*8..g*8+7
      async16(Ad + g * 256, Ab + (g * 8 + a_r) * 16384 + k0 + a_c * 4);
    }
    async16(Bd + w * 512, wT + (w * 16 + b_r) * 1024 + k0 + b_c * 8);
  };

  auto compute = [&](int buf) {
    const float*  Ac = Al + buf * 4096;
    const bf16_t* Bc = Bl + buf * 2048;
    int ca = ((quad * 2) ^ (l15 & 7)) << 2;      // fp32 elem offset within row
    const float* Ar0 = Ac + (w * 32 + l15) * 32;
    const float* Ar1 = Ar0 + 16 * 32;
    f32x4 lo0 = *reinterpret_cast<const f32x4*>(Ar0 + ca);
    f32x4 hi0 = *reinterpret_cast<const f32x4*>(Ar0 + (ca ^ 4));
    f32x4 lo1 = *reinterpret_cast<const f32x4*>(Ar1 + ca);
    f32x4 hi1 = *reinterpret_cast<const f32x4*>(Ar1 + (ca ^ 4));
    bf16x8 a0, a1;
#pragma unroll
    for (int jj = 0; jj < 4; jj++) {
      a0[jj] = (bf16_t)lo0[jj]; a0[jj + 4] = (bf16_t)hi0[jj];
      a1[jj] = (bf16_t)lo1[jj]; a1[jj + 4] = (bf16_t)hi1[jj];
    }
    int cb = (quad ^ ((l15 >> 1) & 3)) << 3;     // bf16 elem offset within row
#pragma unroll
    for (int t = 0; t < 4; t++) {
      bf16x8 bb = *reinterpret_cast<const bf16x8*>(Bc + (t * 16 + l15) * 32 + cb);
      acc[0][t] = __builtin_amdgcn_mfma_f32_16x16x32_bf16(a0, bb, acc[0][t], 0, 0, 0);
      acc[1][t] = __builtin_amdgcn_mfma_f32_16x16x32_bf16(a1, bb, acc[1][t], 0, 0, 0);
    }
  };

  // prologue: stage tile 0
  stage(0, 0);
  int cur = 0;
  for (int k0 = 0; k0 < 1024 - 32; k0 += 32) {
    stage(cur ^ 1, k0 + 32);                     // prefetch next (5 loads/wave)
    asm volatile("s_waitcnt vmcnt(5)" ::: "memory");  // cur's loads landed; prefetch in flight
    __builtin_amdgcn_s_barrier();                // all waves' cur-tile staging visible
    compute(cur);
    __builtin_amdgcn_s_barrier();                // cur buffer fully consumed
    cur ^= 1;
  }
  asm volatile("s_waitcnt vmcnt(0)" ::: "memory");
  __builtin_amdgcn_s_barrier();
  compute(cur);                                  // last tile; nothing in flight after

  // bias
#pragma unroll
  for (int t = 0; t < 4; t++) {
    float bval = bias[h * 64 + t * 16 + l15];
#pragma unroll
    for (int rt = 0; rt < 2; rt++)
#pragma unroll
      for (int r = 0; r < 4; r++) acc[rt][t][r] += bval;
  }

  if (m < 2) {
    bf16_t* outp = ws + ((m == 0) ? WS_Q : WS_K) + h * (2048 * 64);
#pragma unroll
    for (int t = 0; t < 2; t++) {
      int c_lo = t * 16 + l15;
      float freq = powf(10000.0f, (float)c_lo * (1.0f / 32.0f));
#pragma unroll
      for (int rt = 0; rt < 2; rt++)
#pragma unroll
        for (int r = 0; r < 4; r++) {
          int s = s0 + w * 32 + rt * 16 + quad * 4 + r;
          float ang = (float)s / freq;
          float sv = sinf(ang), cv = cosf(ang);
          float xl = acc[rt][t][r], xh = acc[rt][t + 2][r];
          acc[rt][t][r]     = xl * cv - xh * sv;
          acc[rt][t + 2][r] = xh * cv + xl * sv;
        }
    }
#pragma unroll
    for (int rt = 0; rt < 2; rt++)
#pragma unroll
      for (int t = 0; t < 4; t++)
#pragma unroll
        for (int r = 0; r < 4; r++) {
          int s = s0 + w * 32 + rt * 16 + quad * 4 + r;
          outp[s * 64 + t * 16 + l15] = (bf16_t)acc[rt][t][r];
        }
  } else {
    bf16_t* outp = ws + WS_VT + h * (64 * 2048);
#pragma unroll
    for (int rt = 0; rt < 2; rt++)
#pragma unroll
      for (int t = 0; t < 4; t++) {
        int e = t * 16 + l15;
        int sbase = s0 + w * 32 + rt * 16 + quad * 4;
        bf16x4 v;
#pragma unroll
        for (int r = 0; r < 4; r++) v[r] = (bf16_t)acc[rt][t][r];
        *reinterpret_cast<bf16x4*>(outp + e * 2048 + sbase) = v;
      }
  }
}

// ---------------- flash attention (causal, online softmax), KV-step 128 -----
__global__ __launch_bounds__(256) void attn(bf16_t* __restrict__ ws) {
  __shared__ bf16_t Ql[64 * 72];      // (q, e)
  __shared__ bf16_t Kl[128 * 72];     // (kv, e)
  __shared__ bf16_t Vl[64 * 136];     // (e, kv)
  __shared__ bf16_t Pl[4 * 16 * 136]; // per-wave (q, kv)
  int qt = blockIdx.x, h = blockIdx.y;
  int tid = threadIdx.x, w = tid >> 6, lane = tid & 63, quad = lane >> 4, l15 = lane & 15;
  const bf16_t* qp  = ws + WS_Q  + h * 131072;
  const bf16_t* kp  = ws + WS_K  + h * 131072;
  const bf16_t* vtp = ws + WS_VT + h * 131072;
  bf16_t*       zp  = ws + WS_Z  + h * 131072;
  int s0 = qt * 64;

  // stage Q: 64x64
#pragma unroll
  for (int i = 0; i < 2; i++) {
    int g = tid + i * 256;
    int r = g >> 3, cg = g & 7;
    *reinterpret_cast<uint4*>(Ql + r * 72 + cg * 8) =
        *reinterpret_cast<const uint4*>(qp + (s0 + r) * 64 + cg * 8);
  }

  f32x4 o[4];
#pragma unroll
  for (int t = 0; t < 4; t++) o[t] = (f32x4){0.f, 0.f, 0.f, 0.f};
  float m_i[4], l_i[4];
#pragma unroll
  for (int r = 0; r < 4; r++) { m_i[r] = -__builtin_inff(); l_i[r] = 0.f; }
  bf16_t* Plw = Pl + w * (16 * 136);

  int jmax = qt >> 1;
  for (int j = 0; j <= jmax; j++) {
    __syncthreads();
    // stage K: 128 x 64
#pragma unroll
    for (int i = 0; i < 4; i++) {
      int g = tid + i * 256;
      int r = g >> 3, cg = g & 7;
      *reinterpret_cast<uint4*>(Kl + r * 72 + cg * 8) =
          *reinterpret_cast<const uint4*>(kp + (j * 128 + r) * 64 + cg * 8);
    }
    // stage V^T: 64 x 128
#pragma unroll
    for (int i = 0; i < 4; i++) {
      int g = tid + i * 256;
      int r = g >> 4, cg = g & 15;
      *reinterpret_cast<uint4*>(Vl + r * 136 + cg * 8) =
          *reinterpret_cast<const uint4*>(vtp + r * 2048 + j * 128 + cg * 8);
    }
    __syncthreads();

    // scores: 16 q-rows/wave x 128 kv
    f32x4 sc[8];
#pragma unroll
    for (int t = 0; t < 8; t++) sc[t] = (f32x4){0.f, 0.f, 0.f, 0.f};
#pragma unroll
    for (int ks = 0; ks < 2; ks++) {
      bf16x8 af = *reinterpret_cast<const bf16x8*>(Ql + (w * 16 + l15) * 72 + ks * 32 + quad * 8);
#pragma unroll
      for (int t = 0; t < 8; t++) {
        bf16x8 bfr = *reinterpret_cast<const bf16x8*>(Kl + (t * 16 + l15) * 72 + ks * 32 + quad * 8);
        sc[t] = __builtin_amdgcn_mfma_f32_16x16x32_bf16(af, bfr, sc[t], 0, 0, 0);
      }
    }
    // scale + causal mask
#pragma unroll
    for (int t = 0; t < 8; t++) {
      int kvc = j * 128 + t * 16 + l15;
#pragma unroll
      for (int r = 0; r < 4; r++) {
        int qrow = s0 + w * 16 + quad * 4 + r;
        float sv = sc[t][r] * 0.125f;
        sc[t][r] = (kvc > qrow) ? -1e30f : sv;
      }
    }
    // online softmax (rows shared by 16 lanes of a quad)
    float alpha[4];
#pragma unroll
    for (int r = 0; r < 4; r++) {
      float mx = sc[0][r];
#pragma unroll
      for (int t = 1; t < 8; t++) mx = fmaxf(mx, sc[t][r]);
#pragma unroll
      for (int off = 1; off < 16; off <<= 1) mx = fmaxf(mx, __shfl_xor(mx, off));
      float mn = fmaxf(m_i[r], mx);
      alpha[r] = __expf(m_i[r] - mn);
      float rs = 0.f;
#pragma unroll
      for (int t = 0; t < 8; t++) { sc[t][r] = __expf(sc[t][r] - mn); rs += sc[t][r]; }
#pragma unroll
      for (int off = 1; off < 16; off <<= 1) rs += __shfl_xor(rs, off);
      l_i[r] = l_i[r] * alpha[r] + rs;
      m_i[r] = mn;
    }
    // P (C-layout) -> wave-private LDS (A-layout); no barrier needed
#pragma unroll
    for (int t = 0; t < 8; t++)
#pragma unroll
      for (int r = 0; r < 4; r++)
        Plw[(quad * 4 + r) * 136 + t * 16 + l15] = (bf16_t)sc[t][r];
    // rescale O
#pragma unroll
    for (int t = 0; t < 4; t++)
#pragma unroll
      for (int r = 0; r < 4; r++) o[t][r] *= alpha[r];
    // O += P V  (K-dim = 128)
#pragma unroll
    for (int ks = 0; ks < 4; ks++) {
      bf16x8 af = *reinterpret_cast<const bf16x8*>(Plw + l15 * 136 + ks * 32 + quad * 8);
#pragma unroll
      for (int t = 0; t < 4; t++) {
        bf16x8 bfr = *reinterpret_cast<const bf16x8*>(Vl + (t * 16 + l15) * 136 + ks * 32 + quad * 8);
        o[t] = __builtin_amdgcn_mfma_f32_16x16x32_bf16(af, bfr, o[t], 0, 0, 0);
      }
    }
  }
  // normalize + store z (h,s,e)
  float inv[4];
#pragma unroll
  for (int r = 0; r < 4; r++) inv[r] = 1.0f / l_i[r];
#pragma unroll
  for (int t = 0; t < 4; t++)
#pragma unroll
    for (int r = 0; r < 4; r++) {
      int s = s0 + w * 16 + quad * 4 + r;
      zp[s * 64 + t * 16 + l15] = (bf16_t)(o[t][r] * inv[r]);
    }
}

// ---------------- output projection (fp32 out), 128x128 tile ----------------
__global__ __launch_bounds__(256) void out_proj(const bf16_t* __restrict__ ws,
                                                const float* __restrict__ bo,
                                                float* __restrict__ out) {
  __shared__ bf16_t Zl[128 * 72];   // (s, e)
  __shared__ bf16_t Wl[128 * 72];   // (d, e)
  int st = blockIdx.x >> 3, dt = blockIdx.x & 7, h = blockIdx.y;
  int tid = threadIdx.x, w = tid >> 6, lane = tid & 63, quad = lane >> 4, l15 = lane & 15;
  int s0 = st * 128, d0 = dt * 128;
  const bf16_t* zp = ws + WS_Z + h * 131072;
  const bf16_t* wo = ws + WS_WOT + h * 65536;
#pragma unroll
  for (int i = 0; i < 4; i++) {
    int g = tid + i * 256;
    int r = g >> 3, cg = g & 7;
    *reinterpret_cast<uint4*>(Zl + r * 72 + cg * 8) =
        *reinterpret_cast<const uint4*>(zp + (s0 + r) * 64 + cg * 8);
  }
#pragma unroll
  for (int i = 0; i < 4; i++) {
    int g = tid + i * 256;
    int r = g >> 3, cg = g & 7;
    *reinterpret_cast<uint4*>(Wl + r * 72 + cg * 8) =
        *reinterpret_cast<const uint4*>(wo + (d0 + r) * 64 + cg * 8);
  }
  __syncthreads();
  f32x4 acc[2][8];
#pragma unroll
  for (int rt = 0; rt < 2; rt++)
#pragma unroll
    for (int t = 0; t < 8; t++) acc[rt][t] = (f32x4){0.f, 0.f, 0.f, 0.f};
#pragma unroll
  for (int ks = 0; ks < 2; ks++) {
    bf16x8 a0 = *reinterpret_cast<const bf16x8*>(Zl + (w * 32 + l15) * 72 + ks * 32 + quad * 8);
    bf16x8 a1 = *reinterpret_cast<const bf16x8*>(Zl + (w * 32 + 16 + l15) * 72 + ks * 32 + quad * 8);
#pragma unroll
    for (int t = 0; t < 8; t++) {
      bf16x8 bb = *reinterpret_cast<const bf16x8*>(Wl + (t * 16 + l15) * 72 + ks * 32 + quad * 8);
      acc[0][t] = __builtin_amdgcn_mfma_f32_16x16x32_bf16(a0, bb, acc[0][t], 0, 0, 0);
      acc[1][t] = __builtin_amdgcn_mfma_f32_16x16x32_bf16(a1, bb, acc[1][t], 0, 0, 0);
    }
  }
#pragma unroll
  for (int t = 0; t < 8; t++) {
    float bval = bo[d0 + t * 16 + l15] * (1.0f / 16.0f);
#pragma unroll
    for (int rt = 0; rt < 2; rt++)
#pragma unroll
      for (int r = 0; r < 4; r++) {
        int s = s0 + w * 32 + rt * 16 + quad * 4 + r;
        out[(s * 16 + h) * 1024 + d0 + t * 16 + l15] = acc[rt][t][r] + bval;
      }
  }
}

extern "C" void kernel_launch(void* const* d_in, const int* in_sizes, int n_in,
                              void* d_out, int out_size, void* d_ws, size_t ws_size,
                              hipStream_t stream) {
  const float* xq = (const float*)d_in[0];
  const float* xk = (const float*)d_in[1];
  const float* xv = (const float*)d_in[2];
  const float* wq = (const float*)d_in[3];
  const float* bq = (const float*)d_in[4];
  const float* wk = (const float*)d_in[5];
  const float* bk = (const float*)d_in[6];
  const float* wv = (const float*)d_in[7];
  const float* bv = (const float*)d_in[8];
  const float* wo = (const float*)d_in[9];
  const float* bo = (const float*)d_in[10];
  bf16_t* ws  = (bf16_t*)d_ws;
  float*  out = (float*)d_out;

  hipLaunchKernelGGL(transpose_w, dim3(16, 16, 4), dim3(256), 0, stream, wq, wk, wv, wo, ws);
  hipLaunchKernelGGL(qkv_proj,    dim3(16, 16, 3), dim3(256), 0, stream, xq, xk, xv, bq, bk, bv, ws);
  hipLaunchKernelGGL(attn,        dim3(32, 16),    dim3(256), 0, stream, ws);
  hipLaunchKernelGGL(out_proj,    dim3(128, 16),   dim3(256), 0, stream, ws, bo, out);
}

// Round 4
// 499.950 us; speedup vs baseline: 1.1353x; 1.0491x over previous
//
#include <hip/hip_runtime.h>
#include <hip/hip_bf16.h>
#include <stdint.h>
#include <math.h>

typedef __bf16 bf16_t;
typedef __bf16 bf16x8 __attribute__((ext_vector_type(8)));
typedef __bf16 bf16x4 __attribute__((ext_vector_type(4)));
typedef float  f32x4  __attribute__((ext_vector_type(4)));

#define S_CTX 2048
#define NH    16
#define DM    1024
#define DH    64

// ws layout (bf16 element offsets)
#define WS_WT   0                      // wqT, wkT, wvT: 3 * 16*64*1024  (e,k)
#define WS_WOT  (3*1048576)            // woT: 16*1024*64  (d,e)
#define WS_Q    (4*1048576)            // (h,s,e) 16*2048*64
#define WS_K    (WS_Q  + 2097152)
#define WS_VT   (WS_K  + 2097152)      // (h,e,s)
#define WS_Z    (WS_VT + 2097152)      // (h,s,e)

// async global->LDS, 16B per lane. LDS dest = uniform base + lane*16 (linear).
__device__ __forceinline__ void async16(void* lds, const void* g) {
  __builtin_amdgcn_global_load_lds(
      (const __attribute__((address_space(1))) unsigned int*)g,
      (__attribute__((address_space(3))) unsigned int*)lds, 16, 0, 0);
}

// ---------------- weight transpose: fp32 W(n,R,C) -> bf16 WT(n,C,R) ---------
__global__ __launch_bounds__(256) void transpose_w(const float* __restrict__ wq,
                                                   const float* __restrict__ wk,
                                                   const float* __restrict__ wv,
                                                   const float* __restrict__ wo,
                                                   bf16_t* __restrict__ ws) {
  __shared__ bf16_t tl[64 * 68];
  int m = blockIdx.z, h = blockIdx.y, t = blockIdx.x, tid = threadIdx.x;
  const float* in; bf16_t* out; int R, C, r0, c0;
  if (m < 3) { in = (m == 0) ? wq : (m == 1) ? wk : wv; out = ws + m * 1048576;
               R = 1024; C = 64; r0 = t * 64; c0 = 0; }
  else       { in = wo; out = ws + WS_WOT; R = 64; C = 1024; r0 = 0; c0 = t * 64; }
  in  += h * 65536;
  out += h * 65536;
#pragma unroll
  for (int i = 0; i < 4; i++) {
    int idx = tid + i * 256;
    int r = idx >> 4, c = (idx & 15) << 2;
    float4 v = *reinterpret_cast<const float4*>(in + (r0 + r) * C + c0 + c);
    bf16x4 b;
    b[0] = (bf16_t)v.x; b[1] = (bf16_t)v.y; b[2] = (bf16_t)v.z; b[3] = (bf16_t)v.w;
    *reinterpret_cast<bf16x4*>(tl + r * 68 + c) = b;
  }
  __syncthreads();
#pragma unroll
  for (int i = 0; i < 2; i++) {
    int oc = (tid >> 3) + i * 32, ok = (tid & 7) << 3;
    bf16x8 v;
#pragma unroll
    for (int j = 0; j < 8; j++) v[j] = tl[(ok + j) * 68 + oc];
    *reinterpret_cast<bf16x8*>(out + (c0 + oc) * R + r0 + ok) = v;
  }
}

// ---------------- QKV projection + rotary -----------------------------------
// 128 s-rows x 64 cols per block, K-step 32, double-buffered, counted vmcnt.
// Per-block K-phase rotation so concurrent 128B requests across the GPU
// span all 32 k-offsets (decorrelates HBM channel-select bits [7:12]).
__global__ __launch_bounds__(256, 4) void qkv_proj(const float* __restrict__ xq,
                                                   const float* __restrict__ xk,
                                                   const float* __restrict__ xv,
                                                   const float* __restrict__ bq,
                                                   const float* __restrict__ bk,
                                                   const float* __restrict__ bv,
                                                   bf16_t* __restrict__ ws) {
  __shared__ __attribute__((aligned(16))) float  Al[2 * 128 * 32];  // 2x16KB
  __shared__ __attribute__((aligned(16))) bf16_t Bl[2 * 64 * 32];   // 2x4KB
  int st = blockIdx.x, h = blockIdx.y, m = blockIdx.z;
  int tid = threadIdx.x, w = tid >> 6, lane = tid & 63, quad = lane >> 4, l15 = lane & 15;
  const float*  in   = (m == 0) ? xq : (m == 1) ? xk : xv;
  const bf16_t* wT   = ws + m * 1048576 + h * 65536;
  const float*  bias = (m == 0) ? bq : (m == 1) ? bk : bv;
  int s0 = st * 128;
  const float* Ab = in + (s0 * 16 + h) * 1024;   // row stride 16*1024 floats

  // per-lane staging geometry (BK=32)
  int a_r = lane >> 3;                 // 0..7  row within 8-row group (A row = 128B)
  int a_c = (lane & 7) ^ a_r;          // source pre-swizzle: chunk ^= row&7
  int b_r = lane >> 2;                 // 0..15 row within 16-row group (B row = 64B)
  int b_c = (lane & 3) ^ ((lane >> 3) & 3);   // chunk ^= (row>>1)&3

  f32x4 acc[2][4];
#pragma unroll
  for (int rt = 0; rt < 2; rt++)
#pragma unroll
    for (int t = 0; t < 4; t++) acc[rt][t] = (f32x4){0.f, 0.f, 0.f, 0.f};

  auto stage = [&](int buf, int k0) {
    float*  Ad = Al + buf * 4096;
    bf16_t* Bd = Bl + buf * 2048;
#pragma unroll
    for (int i = 0; i < 4; i++) {
      int g = w * 4 + i;               // 0..15, covers rows g*8..g*8+7
      async16(Ad + g * 256, Ab + (g * 8 + a_r) * 16384 + k0 + a_c * 4);
    }
    async16(Bd + w * 512, wT + (w * 16 + b_r) * 1024 + k0 + b_c * 8);
  };

  auto compute = [&](int buf) {
    const float*  Ac = Al + buf * 4096;
    const bf16_t* Bc = Bl + buf * 2048;
    int ca = ((quad * 2) ^ (l15 & 7)) << 2;      // fp32 elem offset within row
    const float* Ar0 = Ac + (w * 32 + l15) * 32;
    const float* Ar1 = Ar0 + 16 * 32;
    f32x4 lo0 = *reinterpret_cast<const f32x4*>(Ar0 + ca);
    f32x4 hi0 = *reinterpret_cast<const f32x4*>(Ar0 + (ca ^ 4));
    f32x4 lo1 = *reinterpret_cast<const f32x4*>(Ar1 + ca);
    f32x4 hi1 = *reinterpret_cast<const f32x4*>(Ar1 + (ca ^ 4));
    bf16x8 a0, a1;
#pragma unroll
    for (int jj = 0; jj < 4; jj++) {
      a0[jj] = (bf16_t)lo0[jj]; a0[jj + 4] = (bf16_t)hi0[jj];
      a1[jj] = (bf16_t)lo1[jj]; a1[jj + 4] = (bf16_t)hi1[jj];
    }
    int cb = (quad ^ ((l15 >> 1) & 3)) << 3;     // bf16 elem offset within row
#pragma unroll
    for (int t = 0; t < 4; t++) {
      bf16x8 bb = *reinterpret_cast<const bf16x8*>(Bc + (t * 16 + l15) * 32 + cb);
      acc[0][t] = __builtin_amdgcn_mfma_f32_16x16x32_bf16(a0, bb, acc[0][t], 0, 0, 0);
      acc[1][t] = __builtin_amdgcn_mfma_f32_16x16x32_bf16(a1, bb, acc[1][t], 0, 0, 0);
    }
  };

  // per-block K-phase rotation (accumulation is commutative)
  int phase = ((st * 7) ^ (h * 3) ^ (m * 13)) & 31;

  stage(0, ((phase + 0) & 31) * 32);
  int cur = 0;
  for (int i = 0; i < 31; i++) {
    stage(cur ^ 1, ((phase + i + 1) & 31) * 32);      // prefetch next tile
    asm volatile("s_waitcnt vmcnt(5)" ::: "memory");  // cur landed; prefetch in flight
    __builtin_amdgcn_s_barrier();
    compute(cur);
    __builtin_amdgcn_s_barrier();
    cur ^= 1;
  }
  asm volatile("s_waitcnt vmcnt(0)" ::: "memory");
  __builtin_amdgcn_s_barrier();
  compute(cur);

  // bias
#pragma unroll
  for (int t = 0; t < 4; t++) {
    float bval = bias[h * 64 + t * 16 + l15];
#pragma unroll
    for (int rt = 0; rt < 2; rt++)
#pragma unroll
      for (int r = 0; r < 4; r++) acc[rt][t][r] += bval;
  }

  if (m < 2) {
    bf16_t* outp = ws + ((m == 0) ? WS_Q : WS_K) + h * (2048 * 64);
#pragma unroll
    for (int t = 0; t < 2; t++) {
      int c_lo = t * 16 + l15;
      float freq = powf(10000.0f, (float)c_lo * (1.0f / 32.0f));
#pragma unroll
      for (int rt = 0; rt < 2; rt++)
#pragma unroll
        for (int r = 0; r < 4; r++) {
          int s = s0 + w * 32 + rt * 16 + quad * 4 + r;
          float ang = (float)s / freq;
          float sv = sinf(ang), cv = cosf(ang);
          float xl = acc[rt][t][r], xh = acc[rt][t + 2][r];
          acc[rt][t][r]     = xl * cv - xh * sv;
          acc[rt][t + 2][r] = xh * cv + xl * sv;
        }
    }
#pragma unroll
    for (int rt = 0; rt < 2; rt++)
#pragma unroll
      for (int t = 0; t < 4; t++)
#pragma unroll
        for (int r = 0; r < 4; r++) {
          int s = s0 + w * 32 + rt * 16 + quad * 4 + r;
          outp[s * 64 + t * 16 + l15] = (bf16_t)acc[rt][t][r];
        }
  } else {
    bf16_t* outp = ws + WS_VT + h * (64 * 2048);
#pragma unroll
    for (int rt = 0; rt < 2; rt++)
#pragma unroll
      for (int t = 0; t < 4; t++) {
        int e = t * 16 + l15;
        int sbase = s0 + w * 32 + rt * 16 + quad * 4;
        bf16x4 v;
#pragma unroll
        for (int r = 0; r < 4; r++) v[r] = (bf16_t)acc[rt][t][r];
        *reinterpret_cast<bf16x4*>(outp + e * 2048 + sbase) = v;
      }
  }
}

// ---------------- flash attention (causal, online softmax), KV-step 128 -----
// Balanced q-tile remap: p = f&255 encodes (h = p>>4, ql = p&15);
// qt = (f>=256) ? 31-ql : ql. Blocks f and f+256 (same CU under round-robin)
// get complementary causal work: (ql/2+1) + ((31-ql)/2+1) = 17 steps, all ql.
__global__ __launch_bounds__(256) void attn(bf16_t* __restrict__ ws) {
  __shared__ bf16_t Ql[64 * 72];      // (q, e)
  __shared__ bf16_t Kl[128 * 72];     // (kv, e)
  __shared__ bf16_t Vl[64 * 136];     // (e, kv)
  __shared__ bf16_t Pl[4 * 16 * 136]; // per-wave (q, kv)
  int f = blockIdx.x + 32 * blockIdx.y;      // 0..511
  int p = f & 255;
  int h  = p >> 4;                           // 0..15
  int ql = p & 15;                           // 0..15
  int qt = (f >> 8) ? (31 - ql) : ql;        // full 32x16 coverage, each once
  int tid = threadIdx.x, w = tid >> 6, lane = tid & 63, quad = lane >> 4, l15 = lane & 15;
  const bf16_t* qp  = ws + WS_Q  + h * 131072;
  const bf16_t* kp  = ws + WS_K  + h * 131072;
  const bf16_t* vtp = ws + WS_VT + h * 131072;
  bf16_t*       zp  = ws + WS_Z  + h * 131072;
  int s0 = qt * 64;

  // stage Q: 64x64
#pragma unroll
  for (int i = 0; i < 2; i++) {
    int g = tid + i * 256;
    int r = g >> 3, cg = g & 7;
    *reinterpret_cast<uint4*>(Ql + r * 72 + cg * 8) =
        *reinterpret_cast<const uint4*>(qp + (s0 + r) * 64 + cg * 8);
  }

  f32x4 o[4];
#pragma unroll
  for (int t = 0; t < 4; t++) o[t] = (f32x4){0.f, 0.f, 0.f, 0.f};
  float m_i[4], l_i[4];
#pragma unroll
  for (int r = 0; r < 4; r++) { m_i[r] = -__builtin_inff(); l_i[r] = 0.f; }
  bf16_t* Plw = Pl + w * (16 * 136);

  int jmax = qt >> 1;
  for (int j = 0; j <= jmax; j++) {
    __syncthreads();
    // stage K: 128 x 64
#pragma unroll
    for (int i = 0; i < 4; i++) {
      int g = tid + i * 256;
      int r = g >> 3, cg = g & 7;
      *reinterpret_cast<uint4*>(Kl + r * 72 + cg * 8) =
          *reinterpret_cast<const uint4*>(kp + (j * 128 + r) * 64 + cg * 8);
    }
    // stage V^T: 64 x 128
#pragma unroll
    for (int i = 0; i < 4; i++) {
      int g = tid + i * 256;
      int r = g >> 4, cg = g & 15;
      *reinterpret_cast<uint4*>(Vl + r * 136 + cg * 8) =
          *reinterpret_cast<const uint4*>(vtp + r * 2048 + j * 128 + cg * 8);
    }
    __syncthreads();

    // scores: 16 q-rows/wave x 128 kv
    f32x4 sc[8];
#pragma unroll
    for (int t = 0; t < 8; t++) sc[t] = (f32x4){0.f, 0.f, 0.f, 0.f};
#pragma unroll
    for (int ks = 0; ks < 2; ks++) {
      bf16x8 af = *reinterpret_cast<const bf16x8*>(Ql + (w * 16 + l15) * 72 + ks * 32 + quad * 8);
#pragma unroll
      for (int t = 0; t < 8; t++) {
        bf16x8 bfr = *reinterpret_cast<const bf16x8*>(Kl + (t * 16 + l15) * 72 + ks * 32 + quad * 8);
        sc[t] = __builtin_amdgcn_mfma_f32_16x16x32_bf16(af, bfr, sc[t], 0, 0, 0);
      }
    }
    // scale + causal mask
#pragma unroll
    for (int t = 0; t < 8; t++) {
      int kvc = j * 128 + t * 16 + l15;
#pragma unroll
      for (int r = 0; r < 4; r++) {
        int qrow = s0 + w * 16 + quad * 4 + r;
        float sv = sc[t][r] * 0.125f;
        sc[t][r] = (kvc > qrow) ? -1e30f : sv;
      }
    }
    // online softmax (rows shared by 16 lanes of a quad)
    float alpha[4];
#pragma unroll
    for (int r = 0; r < 4; r++) {
      float mx = sc[0][r];
#pragma unroll
      for (int t = 1; t < 8; t++) mx = fmaxf(mx, sc[t][r]);
#pragma unroll
      for (int off = 1; off < 16; off <<= 1) mx = fmaxf(mx, __shfl_xor(mx, off));
      float mn = fmaxf(m_i[r], mx);
      alpha[r] = __expf(m_i[r] - mn);
      float rs = 0.f;
#pragma unroll
      for (int t = 0; t < 8; t++) { sc[t][r] = __expf(sc[t][r] - mn); rs += sc[t][r]; }
#pragma unroll
      for (int off = 1; off < 16; off <<= 1) rs += __shfl_xor(rs, off);
      l_i[r] = l_i[r] * alpha[r] + rs;
      m_i[r] = mn;
    }
    // P (C-layout) -> wave-private LDS (A-layout); no barrier needed
#pragma unroll
    for (int t = 0; t < 8; t++)
#pragma unroll
      for (int r = 0; r < 4; r++)
        Plw[(quad * 4 + r) * 136 + t * 16 + l15] = (bf16_t)sc[t][r];
    // rescale O
#pragma unroll
    for (int t = 0; t < 4; t++)
#pragma unroll
      for (int r = 0; r < 4; r++) o[t][r] *= alpha[r];
    // O += P V  (K-dim = 128)
#pragma unroll
    for (int ks = 0; ks < 4; ks++) {
      bf16x8 af = *reinterpret_cast<const bf16x8*>(Plw + l15 * 136 + ks * 32 + quad * 8);
#pragma unroll
      for (int t = 0; t < 4; t++) {
        bf16x8 bfr = *reinterpret_cast<const bf16x8*>(Vl + (t * 16 + l15) * 136 + ks * 32 + quad * 8);
        o[t] = __builtin_amdgcn_mfma_f32_16x16x32_bf16(af, bfr, o[t], 0, 0, 0);
      }
    }
  }
  // normalize + store z (h,s,e)
  float inv[4];
#pragma unroll
  for (int r = 0; r < 4; r++) inv[r] = 1.0f / l_i[r];
#pragma unroll
  for (int t = 0; t < 4; t++)
#pragma unroll
    for (int r = 0; r < 4; r++) {
      int s = s0 + w * 16 + quad * 4 + r;
      zp[s * 64 + t * 16 + l15] = (bf16_t)(o[t][r] * inv[r]);
    }
}

// ---------------- output projection (fp32 out), 128x128 tile ----------------
__global__ __launch_bounds__(256) void out_proj(const bf16_t* __restrict__ ws,
                                                const float* __restrict__ bo,
                                                float* __restrict__ out) {
  __shared__ bf16_t Zl[128 * 72];   // (s, e)
  __shared__ bf16_t Wl[128 * 72];   // (d, e)
  int st = blockIdx.x >> 3, dt = blockIdx.x & 7, h = blockIdx.y;
  int tid = threadIdx.x, w = tid >> 6, lane = tid & 63, quad = lane >> 4, l15 = lane & 15;
  int s0 = st * 128, d0 = dt * 128;
  const bf16_t* zp = ws + WS_Z + h * 131072;
  const bf16_t* wo = ws + WS_WOT + h * 65536;
#pragma unroll
  for (int i = 0; i < 4; i++) {
    int g = tid + i * 256;
    int r = g >> 3, cg = g & 7;
    *reinterpret_cast<uint4*>(Zl + r * 72 + cg * 8) =
        *reinterpret_cast<const uint4*>(zp + (s0 + r) * 64 + cg * 8);
  }
#pragma unroll
  for (int i = 0; i < 4; i++) {
    int g = tid + i * 256;
    int r = g >> 3, cg = g & 7;
    *reinterpret_cast<uint4*>(Wl + r * 72 + cg * 8) =
        *reinterpret_cast<const uint4*>(wo + (d0 + r) * 64 + cg * 8);
  }
  __syncthreads();
  f32x4 acc[2][8];
#pragma unroll
  for (int rt = 0; rt < 2; rt++)
#pragma unroll
    for (int t = 0; t < 8; t++) acc[rt][t] = (f32x4){0.f, 0.f, 0.f, 0.f};
#pragma unroll
  for (int ks = 0; ks < 2; ks++) {
    bf16x8 a0 = *reinterpret_cast<const bf16x8*>(Zl + (w * 32 + l15) * 72 + ks * 32 + quad * 8);
    bf16x8 a1 = *reinterpret_cast<const bf16x8*>(Zl + (w * 32 + 16 + l15) * 72 + ks * 32 + quad * 8);
#pragma unroll
    for (int t = 0; t < 8; t++) {
      bf16x8 bb = *reinterpret_cast<const bf16x8*>(Wl + (t * 16 + l15) * 72 + ks * 32 + quad * 8);
      acc[0][t] = __builtin_amdgcn_mfma_f32_16x16x32_bf16(a0, bb, acc[0][t], 0, 0, 0);
      acc[1][t] = __builtin_amdgcn_mfma_f32_16x16x32_bf16(a1, bb, acc[1][t], 0, 0, 0);
    }
  }
#pragma unroll
  for (int t = 0; t < 8; t++) {
    float bval = bo[d0 + t * 16 + l15] * (1.0f / 16.0f);
#pragma unroll
    for (int rt = 0; rt < 2; rt++)
#pragma unroll
      for (int r = 0; r < 4; r++) {
        int s = s0 + w * 32 + rt * 16 + quad * 4 + r;
        out[(s * 16 + h) * 1024 + d0 + t * 16 + l15] = acc[rt][t][r] + bval;
      }
  }
}

extern "C" void kernel_launch(void* const* d_in, const int* in_sizes, int n_in,
                              void* d_out, int out_size, void* d_ws, size_t ws_size,
                              hipStream_t stream) {
  const float* xq = (const float*)d_in[0];
  const float* xk = (const float*)d_in[1];
  const float* xv = (const float*)d_in[2];
  const float* wq = (const float*)d_in[3];
  const float* bq = (const float*)d_in[4];
  const float* wk = (const float*)d_in[5];
  const float* bk = (const float*)d_in[6];
  const float* wv = (const float*)d_in[7];
  const float* bv = (const float*)d_in[8];
  const float* wo = (const float*)d_in[9];
  const float* bo = (const float*)d_in[10];
  bf16_t* ws  = (bf16_t*)d_ws;
  float*  out = (float*)d_out;

  hipLaunchKernelGGL(transpose_w, dim3(16, 16, 4), dim3(256), 0, stream, wq, wk, wv, wo, ws);
  hipLaunchKernelGGL(qkv_proj,    dim3(16, 16, 3), dim3(256), 0, stream, xq, xk, xv, bq, bk, bv, ws);
  hipLaunchKernelGGL(attn,        dim3(32, 16),    dim3(256), 0, stream, ws);
  hipLaunchKernelGGL(out_proj,    dim3(128, 16),   dim3(256), 0, stream, ws, bo, out);
}